// Round 4
// baseline (747.027 us; speedup 1.0000x reference)
//
#include <hip/hip_runtime.h>
#include <hip/hip_bf16.h>
#include <stdint.h>

// LittleBitLinear: y = [(x*v2) @ sign(V)^T * (v1*u2)] @ sign(U)^T * u1  (x2 branches) + bias
// All inputs FLOAT32, output FLOAT32. Fold scales into binarized weights -> two bf16 GEMMs.
//   Xb  [8192][4096]  bf16 copy of x
//   Wb1 [2048][4096]  bf16 (B^T layout), rows 0..1023 branch1, 1024..2047 branch2
//   H   [8192][2048]  bf16 = Xb @ Wb1^T
//   Wb2 [4096][2048]  bf16 (B^T layout), K-concat of both branches, scaled by u1
//   Y   [8192][4096]  fp32 = H @ Wb2^T + bias
//
// Round 8: round-7 (256x256, 8 waves, 212 unified regs) pinned occupancy at
// 1 block/CU -> lockstep phases fully exposed (MfmaUtil 24%, wall 4375cy/step
// vs 1242cy MFMA work). Fix: keep per-wave 128x64 (32 MFMA + 12 ds_read/step)
// but shrink block to 256x128 with 4 waves (2Mx2N), 48KB LDS, ~196 regs ->
// 2 waves/SIMD = 2 CO-RESIDENT BLOCKS/CU. Block X's MFMA phase now covers
// block Y's ds_read/vmcnt/barrier phase (the m97/m103 overlap mechanism that
// round-7's geometry destroyed), while keeping round-7's FLOP/LDS-byte.
//  - counted vmcnt(6) (6 loads/tile/thread), prefetch-before-wait, NEVER
//    vmcnt(0) in the main loop.
//  - G=4 column-group XCD swizzle: per-XCD B footprint 4 panels (2-4MB,
//    L2-resident); A re-sweeps absorbed by L3.
// NOTE: LDS dest pointer must be a real addrspace(3) cast of the shared-mem
// pointer (compiler addrspacecast). (uint32_t)(uintptr_t) truncation = garbage.

typedef __bf16 bf16x8 __attribute__((ext_vector_type(8)));
typedef float f32x4 __attribute__((ext_vector_type(4)));

__device__ __forceinline__ void async_copy16(const void* g, void* l) {
  __builtin_amdgcn_global_load_lds(
      (const __attribute__((address_space(1))) uint32_t*)g,
      (__attribute__((address_space(3))) uint32_t*)l,
      16, 0, 0);
}

__device__ __forceinline__ float sgn(float v) {
  return (v > 0.f) ? 1.f : ((v < 0.f) ? -1.f : 0.f);
}

__device__ __forceinline__ void store_out(float* p, float v) { *p = v; }
__device__ __forceinline__ void store_out(__hip_bfloat16* p, float v) { *p = __float2bfloat16(v); }

// fp32 -> bf16, 8 elements/thread, vectorized
__global__ __launch_bounds__(256) void convert_x(const float* __restrict__ x,
                                                 __hip_bfloat16* __restrict__ xb,
                                                 int n) {
  int i = (blockIdx.x * 256 + threadIdx.x) * 8;
  if (i >= n) return;
  const float4* p0 = (const float4*)(x + i);
  float4 a = p0[0], b = p0[1];
  __hip_bfloat16 o[8] = {
      __float2bfloat16(a.x), __float2bfloat16(a.y), __float2bfloat16(a.z), __float2bfloat16(a.w),
      __float2bfloat16(b.x), __float2bfloat16(b.y), __float2bfloat16(b.z), __float2bfloat16(b.w)};
  *(uint4*)(xb + i) = *(const uint4*)o;
}

// Wb1[s][k] = sign(V[s][k]) * v2[k] * v1[s] * u2[s]   (s<1024: branch1, else branch2)
__global__ __launch_bounds__(256) void prep_w1(
    const float* __restrict__ V, const float* __restrict__ v2,
    const float* __restrict__ v1, const float* __restrict__ u2,
    const float* __restrict__ V_R, const float* __restrict__ v2_R,
    const float* __restrict__ v1_R, const float* __restrict__ u2_R,
    __hip_bfloat16* __restrict__ W) {
  int g = blockIdx.x * 256 + threadIdx.x;  // one thread -> 8 consecutive k
  int k = (g & 511) * 8;                   // 4096 / 8 = 512 groups per row
  int s = g >> 9;                          // 0..2047
  const float *Vp, *v2p;
  float rs;
  if (s < 1024) {
    Vp = V + s * 4096 + k; v2p = v2 + k; rs = v1[s] * u2[s];
  } else {
    int ss = s - 1024;
    Vp = V_R + ss * 4096 + k; v2p = v2_R + k; rs = v1_R[ss] * u2_R[ss];
  }
  __hip_bfloat16 o[8];
#pragma unroll
  for (int e = 0; e < 8; ++e)
    o[e] = __float2bfloat16(sgn(Vp[e]) * v2p[e] * rs);
  *(uint4*)(W + s * 4096 + k) = *(const uint4*)o;
}

// Wb2[j][s] = sign(U[j][s]) * u1[j]  (s<1024 branch1, else branch2)
__global__ __launch_bounds__(256) void prep_w2(
    const float* __restrict__ U, const float* __restrict__ u1,
    const float* __restrict__ U_R, const float* __restrict__ u1_R,
    __hip_bfloat16* __restrict__ W) {
  int g = blockIdx.x * 256 + threadIdx.x;  // one thread -> 8 consecutive s
  int s = (g & 255) * 8;                   // 2048 / 8 = 256 groups per row
  int j = g >> 8;                          // 0..4095
  const float* Up;
  float sc;
  if (s < 1024) { Up = U + j * 1024 + s;            sc = u1[j]; }
  else          { Up = U_R + j * 1024 + (s - 1024); sc = u1_R[j]; }
  __hip_bfloat16 o[8];
#pragma unroll
  for (int e = 0; e < 8; ++e)
    o[e] = __float2bfloat16(sgn(Up[e]) * sc);
  *(uint4*)(W + j * 2048 + s) = *(const uint4*)o;
}

// C[M][N] = A[M][K] @ Bt[N][K]^T (+bias), bf16 in, fp32 acc.
// 256x128 block tile, 4 waves (2Mx2N), each wave 128x64 = 8x4 MFMA 16x16x32.
// BK=32, double-buffered LDS (2 x 24KB). Per buffer:
//   A [0,16K):      slot = chunk*256 + row (chunk = k-octet 0..3, row 0..255)
//   B [16K,24K):    slot = chunk*128 + row (row 0..127)
// cell = 16B (8 bf16). global_load_lds dest = wave base + lane*16.
// Staging per thread per tile: 6 loads (A rows: thread t owns row t, all 4
// chunks; B: slots {t, t+256}).
//
// K-loop (counted vmcnt, 2 barriers/step, prefetch-before-wait):
//   iter t: [bar_A: all waves done reading buf^1 (tile t-1)]
//           stage(t+1 -> buf^1)    <- 6 loads, fly across all of compute(t)
//           s_waitcnt vmcnt(6)     <- tile t's 6 loads landed (t+1's fly)
//           [bar_B: every thread's tile-t loads landed]
//           compute(buf)           <- 12 ds_read_b128 + 32 MFMA per wave
// 2 blocks/CU co-resident: the other block's compute covers this block's
// read/sync phase.
template <typename OutT>
__global__ __launch_bounds__(256, 2) void gemm_bt(
    const __hip_bfloat16* __restrict__ A,
    const __hip_bfloat16* __restrict__ Bt,
    OutT* __restrict__ C,
    const float* __restrict__ bias,
    int K, int N) {
  __shared__ char smem[49152];  // 2 buffers x (A 16KB + B 8KB)
  const int t = threadIdx.x;
  const int lane = t & 63;
  const int w = t >> 6;
  const int wm = (w >> 1) << 7;   // 0 / 128
  const int wn = (w & 1) << 6;    // 0 / 64

  // L2-aware block swizzle: column-group-major (G=4 block-cols per group),
  // then contiguous chunk per XCD (nwg % 8 == 0 for our grids).
  const int gx = gridDim.x;
  const int gy = gridDim.y;
  const int nwg = gx * gy;
  int lin = blockIdx.y * gx + blockIdx.x;
  {
    const int xcd = lin & 7, idx = lin >> 3, q = nwg >> 3;
    lin = xcd * q + idx;
  }
  const int grpsz = gy << 2;          // gy rows * 4 cols per group
  const int cg = lin / grpsz;
  const int rem = lin - cg * grpsz;
  const int bm = (rem >> 2) << 8;                  // row block * 256
  const int bn = ((cg << 2) + (rem & 3)) << 7;     // col block * 128

  const int quad = lane >> 4;
  const int l16 = lane & 15;

  f32x4 acc[8][4] = {};

  // staging addresses (thread t):
  //   A: row t, chunks 0..3  -> lds oA + j*4096, global gA + k0 + j*8
  //   B: slots {t, t+256}    -> lds oB, oB+4096; global gB + k0 + {0,16}
  const __hip_bfloat16* gA = A + (bm + t) * K;
  const __hip_bfloat16* gB = Bt + (bn + (t & 127)) * K + ((t >> 7) << 3);
  const int oA = t * 16;
  const int oB = 16384 + t * 16;

  auto stage = [&](int k0, int bufOff) {
    char* base = smem + bufOff;
    async_copy16(gA + k0,      base + oA);
    async_copy16(gA + k0 + 8,  base + oA + 4096);
    async_copy16(gA + k0 + 16, base + oA + 8192);
    async_copy16(gA + k0 + 24, base + oA + 12288);
    async_copy16(gB + k0,      base + oB);
    async_copy16(gB + k0 + 16, base + oB + 4096);
  };
  auto compute = [&](int bufOff) {
    const char* base = smem + bufOff;
    bf16x8 a[8], b[4];
#pragma unroll
    for (int j = 0; j < 4; ++j)
      b[j] = *(const bf16x8*)(base + 16384 + (quad << 11) + ((wn + (j << 4) + l16) << 4));
#pragma unroll
    for (int i = 0; i < 8; ++i)
      a[i] = *(const bf16x8*)(base + (quad << 12) + ((wm + (i << 4) + l16) << 4));
#pragma unroll
    for (int i = 0; i < 8; ++i)
#pragma unroll
      for (int j = 0; j < 4; ++j)
        acc[i][j] = __builtin_amdgcn_mfma_f32_16x16x32_bf16(a[i], b[j], acc[i][j], 0, 0, 0);
  };

  const int NT = K >> 5;  // K/32 tiles
  stage(0, 0);
  int cur = 0;
  for (int tt = 0; tt < NT; ++tt) {
    if (tt > 0) {
      __builtin_amdgcn_s_barrier();          // bar_A: buf^1's readers are done
      asm volatile("" ::: "memory");
    }
    if (tt + 1 < NT) {
      stage((tt + 1) << 5, cur ^ 24576);     // prefetch next tile
      asm volatile("s_waitcnt vmcnt(6)" ::: "memory");  // tile t landed
    } else {
      asm volatile("s_waitcnt vmcnt(0)" ::: "memory");  // last tile: drain
    }
    __builtin_amdgcn_s_barrier();            // bar_B: all threads' tile-t landed
    asm volatile("" ::: "memory");
    compute(cur);
    cur ^= 24576;
  }

  // epilogue: C/D layout col=lane&15, row=quad*4+reg
#pragma unroll
  for (int j = 0; j < 4; ++j) {
    int col = bn + wn + (j << 4) + l16;
    float bv = bias ? bias[col] : 0.0f;
#pragma unroll
    for (int i = 0; i < 8; ++i) {
      int row0 = bm + wm + (i << 4) + (quad << 2);
#pragma unroll
      for (int r = 0; r < 4; ++r)
        store_out(&C[(row0 + r) * N + col], acc[i][j][r] + bv);
    }
  }
}

extern "C" void kernel_launch(void* const* d_in, const int* in_sizes, int n_in,
                              void* d_out, int out_size, void* d_ws, size_t ws_size,
                              hipStream_t stream) {
  const float* x    = (const float*)d_in[0];
  const float* V    = (const float*)d_in[1];
  const float* U    = (const float*)d_in[2];
  const float* v2   = (const float*)d_in[3];
  const float* v1   = (const float*)d_in[4];
  const float* u2   = (const float*)d_in[5];
  const float* u1   = (const float*)d_in[6];
  const float* V_R  = (const float*)d_in[7];
  const float* U_R  = (const float*)d_in[8];
  const float* v2_R = (const float*)d_in[9];
  const float* v1_R = (const float*)d_in[10];
  const float* u2_R = (const float*)d_in[11];
  const float* u1_R = (const float*)d_in[12];
  const float* bias = (const float*)d_in[13];

  __hip_bfloat16* Xb  = (__hip_bfloat16*)d_ws;          // 8192*4096
  __hip_bfloat16* Wb1 = Xb + 8192 * 4096;               // 2048*4096
  __hip_bfloat16* Wb2 = Wb1 + 2048 * 4096;              // 4096*2048
  __hip_bfloat16* H   = Wb2 + 4096 * 2048;              // 8192*2048
  float* Y = (float*)d_out;

  const int nx = 8192 * 4096;
  convert_x<<<nx / (256 * 8), 256, 0, stream>>>(x, Xb, nx);
  prep_w1<<<4096, 256, 0, stream>>>(V, v2, v1, u2, V_R, v2_R, v1_R, u2_R, Wb1);
  prep_w2<<<4096, 256, 0, stream>>>(U, u1, U_R, u1_R, Wb2);

  // H[8192][2048] = Xb @ Wb1^T   (grid 16x32 = 512 blocks = 2/CU)
  gemm_bt<__hip_bfloat16><<<dim3(2048 / 128, 8192 / 256), 256, 0, stream>>>(
      Xb, Wb1, H, nullptr, 4096, 2048);
  // Y[8192][4096] = H @ Wb2^T + bias   (grid 32x32 = 1024 blocks)
  gemm_bt<float><<<dim3(4096 / 128, 8192 / 256), 256, 0, stream>>>(
      H, Wb2, Y, bias, 2048, 4096);
}

// Round 5
// 582.209 us; speedup vs baseline: 1.2831x; 1.2831x over previous
//
#include <hip/hip_runtime.h>
#include <hip/hip_bf16.h>
#include <stdint.h>

// LittleBitLinear: y = [(x*v2) @ sign(V)^T * (v1*u2)] @ sign(U)^T * u1  (x2 branches) + bias
// All inputs FLOAT32, output FLOAT32. Fold scales into binarized weights -> two bf16 GEMMs.
//   Xb  [8192][4096]  bf16 copy of x
//   Wb1 [2048][4096]  bf16 (B^T layout), rows 0..1023 branch1, 1024..2047 branch2
//   H   [8192][2048]  bf16 = Xb @ Wb1^T
//   Wb2 [4096][2048]  bf16 (B^T layout), K-concat of both branches, scaled by u1
//   Y   [8192][4096]  fp32 = H @ Wb2^T + bias
//
// Round 9: rounds 2-4 proved the 2-phase lockstep saturates at ~24% MfmaUtil at
// ANY tile size / blocks-per-CU (m233 mechanism: stage+vmcnt+barrier is ~72% of
// the critical path). This round ports the m201 8-phase schedule:
//   256x256 tile, BK=64, 8 waves (2Mx4N), 128KB LDS = 2 K-tile buffers (fixed
//   parity, no flip). Iter i computes tiles T=2i (buf0, phases 1-4) and T+1
//   (buf1, phases 5-8). Per phase: {ds_read subtile || stage 1 half-tile ->
//   barrier -> 16 MFMA (one C-quadrant x K=64) under setprio(1) -> barrier}.
// Staging schedule (hand-proven race-free; B region of a buf frees after its
// phase-1/5 reg-load, A region after phase 4/8):
//   p1: T+1.A0->buf1  p2: T+1.A1->buf1  p3: T+2.B0->buf0  p4: T+2.B1->buf0
//   p5: T+2.A0->buf0  p6: T+2.A1->buf0  p7: T+3.B0->buf1  p8: T+3.B1->buf1
// vmcnt(4) at p4 and p8 ONLY (leaves the 2 newest half-tiles in flight; every
// staged half has >=3 phases of flight before first consumption). Barriers are
// raw s_barrier (no implicit vmcnt drain) and unconditional (uniform flow).
// LDS bank conflicts: chunk-major 16B-cell layout measured 0 conflicts (r0-r4).
// NOTE: LDS dest of global_load_lds must be wave-uniform base + lane*16, and a
// real addrspace(3) cast (no integer truncation).

typedef __bf16 bf16x8 __attribute__((ext_vector_type(8)));
typedef float f32x4 __attribute__((ext_vector_type(4)));

__device__ __forceinline__ void async_copy16(const void* g, void* l) {
  __builtin_amdgcn_global_load_lds(
      (const __attribute__((address_space(1))) uint32_t*)g,
      (__attribute__((address_space(3))) uint32_t*)l,
      16, 0, 0);
}

__device__ __forceinline__ float sgn(float v) {
  return (v > 0.f) ? 1.f : ((v < 0.f) ? -1.f : 0.f);
}

__device__ __forceinline__ void store_out(float* p, float v) { *p = v; }
__device__ __forceinline__ void store_out(__hip_bfloat16* p, float v) { *p = __float2bfloat16(v); }

// fp32 -> bf16, 8 elements/thread, vectorized
__global__ __launch_bounds__(256) void convert_x(const float* __restrict__ x,
                                                 __hip_bfloat16* __restrict__ xb,
                                                 int n) {
  int i = (blockIdx.x * 256 + threadIdx.x) * 8;
  if (i >= n) return;
  const float4* p0 = (const float4*)(x + i);
  float4 a = p0[0], b = p0[1];
  __hip_bfloat16 o[8] = {
      __float2bfloat16(a.x), __float2bfloat16(a.y), __float2bfloat16(a.z), __float2bfloat16(a.w),
      __float2bfloat16(b.x), __float2bfloat16(b.y), __float2bfloat16(b.z), __float2bfloat16(b.w)};
  *(uint4*)(xb + i) = *(const uint4*)o;
}

// Wb1[s][k] = sign(V[s][k]) * v2[k] * v1[s] * u2[s]   (s<1024: branch1, else branch2)
__global__ __launch_bounds__(256) void prep_w1(
    const float* __restrict__ V, const float* __restrict__ v2,
    const float* __restrict__ v1, const float* __restrict__ u2,
    const float* __restrict__ V_R, const float* __restrict__ v2_R,
    const float* __restrict__ v1_R, const float* __restrict__ u2_R,
    __hip_bfloat16* __restrict__ W) {
  int g = blockIdx.x * 256 + threadIdx.x;  // one thread -> 8 consecutive k
  int k = (g & 511) * 8;                   // 4096 / 8 = 512 groups per row
  int s = g >> 9;                          // 0..2047
  const float *Vp, *v2p;
  float rs;
  if (s < 1024) {
    Vp = V + s * 4096 + k; v2p = v2 + k; rs = v1[s] * u2[s];
  } else {
    int ss = s - 1024;
    Vp = V_R + ss * 4096 + k; v2p = v2_R + k; rs = v1_R[ss] * u2_R[ss];
  }
  __hip_bfloat16 o[8];
#pragma unroll
  for (int e = 0; e < 8; ++e)
    o[e] = __float2bfloat16(sgn(Vp[e]) * v2p[e] * rs);
  *(uint4*)(W + s * 4096 + k) = *(const uint4*)o;
}

// Wb2[j][s] = sign(U[j][s]) * u1[j]  (s<1024 branch1, else branch2)
__global__ __launch_bounds__(256) void prep_w2(
    const float* __restrict__ U, const float* __restrict__ u1,
    const float* __restrict__ U_R, const float* __restrict__ u1_R,
    __hip_bfloat16* __restrict__ W) {
  int g = blockIdx.x * 256 + threadIdx.x;  // one thread -> 8 consecutive s
  int s = (g & 255) * 8;                   // 2048 / 8 = 256 groups per row
  int j = g >> 8;                          // 0..4095
  const float* Up;
  float sc;
  if (s < 1024) { Up = U + j * 1024 + s;            sc = u1[j]; }
  else          { Up = U_R + j * 1024 + (s - 1024); sc = u1_R[j]; }
  __hip_bfloat16 o[8];
#pragma unroll
  for (int e = 0; e < 8; ++e)
    o[e] = __float2bfloat16(sgn(Up[e]) * sc);
  *(uint4*)(W + j * 2048 + s) = *(const uint4*)o;
}

// One phase: (optional) reload B regs, load 2 A-frags x 2 ksubs, run the STAGE
// statement (stage + optional counted vmcnt), barrier, 16 MFMA under setprio,
// barrier. Q is a literal (compile-time acc indices; rule: no runtime indexing).
#define PHASE(Q, BUF, LOADB, STAGE)                                            \
  {                                                                            \
    if (LOADB) {                                                               \
      _Pragma("unroll") for (int j = 0; j < 4; ++j) {                          \
        bfr[j][0] = ldb(BUF, j, 0);                                            \
        bfr[j][1] = ldb(BUF, j, 1);                                            \
      }                                                                        \
    }                                                                          \
    bf16x8 a00 = lda(BUF, 2 * (Q), 0), a01 = lda(BUF, 2 * (Q), 1);             \
    bf16x8 a10 = lda(BUF, 2 * (Q) + 1, 0), a11 = lda(BUF, 2 * (Q) + 1, 1);     \
    STAGE;                                                                     \
    asm volatile("" ::: "memory");                                             \
    __builtin_amdgcn_s_barrier();                                              \
    asm volatile("" ::: "memory");                                             \
    __builtin_amdgcn_s_setprio(1);                                             \
    _Pragma("unroll") for (int j = 0; j < 4; ++j) {                            \
      acc[2 * (Q)][j] = __builtin_amdgcn_mfma_f32_16x16x32_bf16(               \
          a00, bfr[j][0], acc[2 * (Q)][j], 0, 0, 0);                           \
      acc[2 * (Q)][j] = __builtin_amdgcn_mfma_f32_16x16x32_bf16(               \
          a01, bfr[j][1], acc[2 * (Q)][j], 0, 0, 0);                           \
      acc[2 * (Q) + 1][j] = __builtin_amdgcn_mfma_f32_16x16x32_bf16(           \
          a10, bfr[j][0], acc[2 * (Q) + 1][j], 0, 0, 0);                       \
      acc[2 * (Q) + 1][j] = __builtin_amdgcn_mfma_f32_16x16x32_bf16(           \
          a11, bfr[j][1], acc[2 * (Q) + 1][j], 0, 0, 0);                       \
    }                                                                          \
    __builtin_amdgcn_s_setprio(0);                                             \
    asm volatile("" ::: "memory");                                             \
    __builtin_amdgcn_s_barrier();                                              \
    asm volatile("" ::: "memory");                                             \
  }

// C[M][N] = A[M][K] @ Bt[N][K]^T (+bias), bf16 in, fp32 acc.
// 256x256 tile, BK=64, 8 waves (2Mx4N), per-wave 128x64 = 8x4 frags of 16x16.
// LDS 128KB: buf0 [0,64K) = tiles of even K-index, buf1 [64K,128K) = odd.
// Per buf: A [0,32K) cell(row,chunk) at chunk*4096 + row*16 (chunk = k-octet
// 0..7, row 0..255); B [32K,64K) same with N-rows. Half h = rows h*128..+127.
// Staging a half (16KB): wave w stages chunk w, rows r*64+lane (r=0,1):
// dest = w*4096 + h*2048 + r*1024 + lane*16 (wave-uniform base + lane*16).
template <typename OutT>
__global__ __launch_bounds__(512, 2) void gemm_bt(
    const __hip_bfloat16* __restrict__ A,
    const __hip_bfloat16* __restrict__ Bt,
    OutT* __restrict__ C,
    const float* __restrict__ bias,
    int K, int N) {
  __shared__ char smem[131072];
  const int t = threadIdx.x;
  const int lane = t & 63;
  const int w = t >> 6;
  const int wm = (w >> 2) << 7;   // 0 / 128
  const int wn = (w & 3) << 6;    // 0 / 64 / 128 / 192

  // L2-aware block swizzle: column-group-major (G=2 block-cols per group),
  // then contiguous chunk per XCD (nwg % 8 == 0 for our grids).
  const int gx = gridDim.x;
  const int gy = gridDim.y;
  const int nwg = gx * gy;
  int lin = blockIdx.y * gx + blockIdx.x;
  {
    const int xcd = lin & 7, idx = lin >> 3, q = nwg >> 3;
    lin = xcd * q + idx;
  }
  const int grpsz = gy << 1;          // gy rows * 2 cols per group
  const int cg = lin / grpsz;
  const int rem = lin - cg * grpsz;
  const int bm = (rem >> 1) << 8;                  // row block * 256
  const int bn = ((cg << 1) + (rem & 1)) << 8;     // col block * 256

  const int quad = lane >> 4;
  const int l16 = lane & 15;

  f32x4 acc[8][4] = {};
  bf16x8 bfr[4][2];

  const __hip_bfloat16* gAb = A + bm * K;
  const __hip_bfloat16* gBb = Bt + bn * K;

  auto stageA = [&](int k0, int half, int bufOff) {
#pragma unroll
    for (int r = 0; r < 2; ++r)
      async_copy16(gAb + (half * 128 + r * 64 + lane) * K + k0 + w * 8,
                   smem + bufOff + w * 4096 + half * 2048 + r * 1024 + lane * 16);
  };
  auto stageB = [&](int k0, int half, int bufOff) {
#pragma unroll
    for (int r = 0; r < 2; ++r)
      async_copy16(gBb + (half * 128 + r * 64 + lane) * K + k0 + w * 8,
                   smem + bufOff + 32768 + w * 4096 + half * 2048 + r * 1024 + lane * 16);
  };
  auto lda = [&](int bufOff, int i, int s) -> bf16x8 {
    return *(const bf16x8*)(smem + bufOff + ((s << 2) + quad) * 4096 +
                            ((wm + (i << 4) + l16) << 4));
  };
  auto ldb = [&](int bufOff, int j, int s) -> bf16x8 {
    return *(const bf16x8*)(smem + bufOff + 32768 + ((s << 2) + quad) * 4096 +
                            ((wn + (j << 4) + l16) << 4));
  };

  const int NI = K >> 7;  // K / 128: iterations, 2 K-tiles each

  // Prologue: T0 fully (buf0) + T1.B (buf1); T1.A comes at p1-p2 of iter 0.
  stageA(0, 0, 0);
  stageA(0, 1, 0);
  stageB(0, 0, 0);
  stageB(0, 1, 0);
  stageB(64, 0, 65536);
  stageB(64, 1, 65536);
  asm volatile("s_waitcnt vmcnt(4)" ::: "memory");  // T0 landed; T1.B may fly
  __builtin_amdgcn_s_barrier();
  asm volatile("" ::: "memory");

  for (int i = 0; i < NI; ++i) {
    const int kT = i << 7;           // K-offset of tile T = 2i
    const bool full = (i + 1 < NI);  // stage T+2 / T+3 ?
    // ---- K-tile T (buf0), phases 1-4 ----
    PHASE(0, 0, true,  { stageA(kT + 64, 0, 65536); })
    PHASE(1, 0, false, { stageA(kT + 64, 1, 65536); })
    PHASE(2, 0, false, { if (full) stageB(kT + 128, 0, 0); })
    PHASE(3, 0, false, {
      if (full) {
        stageB(kT + 128, 1, 0);
        asm volatile("s_waitcnt vmcnt(4)" ::: "memory");  // T+1 data landed
      } else {
        asm volatile("s_waitcnt vmcnt(0)" ::: "memory");  // drain T+1.A
      }
    })
    // ---- K-tile T+1 (buf1), phases 5-8 ----
    PHASE(0, 65536, true,  { if (full) stageA(kT + 128, 0, 0); })
    PHASE(1, 65536, false, { if (full) stageA(kT + 128, 1, 0); })
    PHASE(2, 65536, false, { if (full) stageB(kT + 192, 0, 65536); })
    PHASE(3, 65536, false, {
      if (full) {
        stageB(kT + 192, 1, 65536);
        asm volatile("s_waitcnt vmcnt(4)" ::: "memory");  // T+2 data landed
      }
    })
  }

  // epilogue: C/D layout col=lane&15, row=quad*4+reg
#pragma unroll
  for (int j = 0; j < 4; ++j) {
    int col = bn + wn + (j << 4) + l16;
    float bv = bias ? bias[col] : 0.0f;
#pragma unroll
    for (int i = 0; i < 8; ++i) {
      int row0 = bm + wm + (i << 4) + (quad << 2);
#pragma unroll
      for (int r = 0; r < 4; ++r)
        store_out(&C[(row0 + r) * N + col], acc[i][j][r] + bv);
    }
  }
}

extern "C" void kernel_launch(void* const* d_in, const int* in_sizes, int n_in,
                              void* d_out, int out_size, void* d_ws, size_t ws_size,
                              hipStream_t stream) {
  const float* x    = (const float*)d_in[0];
  const float* V    = (const float*)d_in[1];
  const float* U    = (const float*)d_in[2];
  const float* v2   = (const float*)d_in[3];
  const float* v1   = (const float*)d_in[4];
  const float* u2   = (const float*)d_in[5];
  const float* u1   = (const float*)d_in[6];
  const float* V_R  = (const float*)d_in[7];
  const float* U_R  = (const float*)d_in[8];
  const float* v2_R = (const float*)d_in[9];
  const float* v1_R = (const float*)d_in[10];
  const float* u2_R = (const float*)d_in[11];
  const float* u1_R = (const float*)d_in[12];
  const float* bias = (const float*)d_in[13];

  __hip_bfloat16* Xb  = (__hip_bfloat16*)d_ws;          // 8192*4096
  __hip_bfloat16* Wb1 = Xb + 8192 * 4096;               // 2048*4096
  __hip_bfloat16* Wb2 = Wb1 + 2048 * 4096;              // 4096*2048
  __hip_bfloat16* H   = Wb2 + 4096 * 2048;              // 8192*2048
  float* Y = (float*)d_out;

  const int nx = 8192 * 4096;
  convert_x<<<nx / (256 * 8), 256, 0, stream>>>(x, Xb, nx);
  prep_w1<<<4096, 256, 0, stream>>>(V, v2, v1, u2, V_R, v2_R, v1_R, u2_R, Wb1);
  prep_w2<<<4096, 256, 0, stream>>>(U, u1, U_R, u1_R, Wb2);

  // H[8192][2048] = Xb @ Wb1^T   (grid 8x32 = 256 blocks = 1/CU, NI=32)
  gemm_bt<__hip_bfloat16><<<dim3(2048 / 256, 8192 / 256), 512, 0, stream>>>(
      Xb, Wb1, H, nullptr, 4096, 2048);
  // Y[8192][4096] = H @ Wb2^T + bias   (grid 16x32 = 512 blocks, NI=16)
  gemm_bt<float><<<dim3(4096 / 256, 8192 / 256), 512, 0, stream>>>(
      H, Wb2, Y, bias, 2048, 4096);
}